// Round 9
// baseline (3492.690 us; speedup 1.0000x reference)
//
#include <hip/hip_runtime.h>
#include <math.h>

#define HH 128
#define WW 128
#define CIN 512
#define NPIX 16384
#define NPRE 6000
#define NPOST 300

// workspace offsets (in floats; LOG is doubles, offset even => 8B aligned)
#define WS_WT      0ull                       // 2359296 floats
#define WS_LOG     2359296ull                 // 16384*12 doubles = 393216 floats
#define WS_FG32    2752512ull                 // 16384 floats
#define WS_ASCALE  2768896ull                 // 16384 floats
#define WS_ASSIGN  2785280ull                 // 16384 ints
#define WS_ROI     2801664ull                 // 16384*4 floats
#define WS_SC32    2867200ull                 // 16384 floats
#define WS_CAND    2883584ull                 // 6000*4 floats
#define WS_TOPS    2907584ull                 // 6000 floats

// d_out offsets (floats), concatenated tuple in return order
#define O_LOCS   0        // 16384*4
#define O_ROIS   65536    // 300*4
#define O_RIDX   66736    // 300
#define O_ANCHOR 67036    // 16384*4
#define O_CLS    132572   // 16384*7
#define O_COS    247260   // 16384
#define O_RSC    263644   // 300
#define O_OLD    263944   // 6000*4

__device__ __forceinline__ float exp32(float x) { return (float)exp((double)x); }
__device__ __forceinline__ float sqrt32(float x) { return (float)sqrt((double)x); }

__global__ __launch_bounds__(1024) void zero_kernel(double* __restrict__ p, int n) {
  int i = blockIdx.x * 1024 + threadIdx.x;
  if (i < n) p[i] = 0.0;
}

// ---------------- weight transpose: w[m][c][k] -> wt[(c*9+k)][m] ----------------
__global__ __launch_bounds__(256) void wt_kernel(const float* __restrict__ w,
                                                 float* __restrict__ wt) {
  __shared__ float t[64][65];
  int ck0 = blockIdx.x * 64;
  int m0  = blockIdx.y * 64;
  int j  = threadIdx.x & 63;
  int i0 = threadIdx.x >> 6;
#pragma unroll
  for (int ii = 0; ii < 16; ++ii) {
    int i = i0 + ii * 4;
    t[i][j] = w[(size_t)(m0 + i) * 4608 + ck0 + j];
  }
  __syncthreads();
#pragma unroll
  for (int ii = 0; ii < 16; ++ii) {
    int jj = i0 + ii * 4;
    wt[(size_t)(ck0 + jj) * 512 + m0 + j] = t[j][jj];
  }
}

// -- fused conv 3x3 SAME (fp64 acc) -> fp32 cast -> per-op bias/relu/mask ------
// -- then 12 head dots (fp64-exact over fp32 h) -> fp64 atomics into logits ----
#define KC 8
__global__ __launch_bounds__(256) void conv_heads_kernel(
    const float* __restrict__ x, const float* __restrict__ wt,
    const float* __restrict__ bias, const int* __restrict__ mask,
    const float* __restrict__ loc_w, const float* __restrict__ cls_w,
    const float* __restrict__ cos_w, double* __restrict__ logits) {
  __shared__ float xs[KC][3][66];
  __shared__ float wsm[KC][9][64];
  __shared__ float w12[12][64];
  int tid = threadIdx.x;
  int tm = tid & 15;
  int tp = tid >> 4;
  int pt = blockIdx.x;  // 0..255
  int mt = blockIdx.y;  // 0..7
  int y  = pt >> 1;
  int xb = (pt & 1) << 6;
  int m0 = mt << 6;

  for (int idx = tid; idx < 12 * 64; idx += 256) {
    int r = idx >> 6, c = idx & 63;
    float v = (r < 4) ? loc_w[r * 512 + m0 + c]
                      : (r < 11) ? cls_w[(r - 4) * 512 + m0 + c] : cos_w[m0 + c];
    w12[r][c] = v;
  }

  double acc[4][4];
#pragma unroll
  for (int a = 0; a < 4; ++a)
#pragma unroll
    for (int b = 0; b < 4; ++b) acc[a][b] = 0.0;

  for (int c0 = 0; c0 < CIN; c0 += KC) {
    for (int idx = tid; idx < KC * 3 * 66; idx += 256) {
      int cc = idx / 198;
      int rem = idx - cc * 198;
      int r = rem / 66;
      int i = rem - r * 66;
      int yy = y - 1 + r;
      int xx = xb - 1 + i;
      float v = 0.f;
      if (yy >= 0 && yy < HH && xx >= 0 && xx < WW)
        v = x[(size_t)(c0 + cc) * NPIX + yy * WW + xx];
      xs[cc][r][i] = v;
    }
    for (int idx = tid; idx < KC * 9 * 16; idx += 256) {
      int mm4 = idx & 15;
      int k = (idx >> 4) % 9;
      int cc = idx / 144;
      float4 v = *(const float4*)&wt[(size_t)((c0 + cc) * 9 + k) * 512 + m0 + mm4 * 4];
      *(float4*)&wsm[cc][k][mm4 * 4] = v;
    }
    __syncthreads();

    for (int cc = 0; cc < KC; ++cc) {
#pragma unroll
      for (int ky = 0; ky < 3; ++ky) {
        const float* xr = &xs[cc][ky][tp << 2];
        double xd[6];
#pragma unroll
        for (int i = 0; i < 6; ++i) xd[i] = (double)xr[i];
#pragma unroll
        for (int kx = 0; kx < 3; ++kx) {
          float4 wv = *(const float4*)&wsm[cc][ky * 3 + kx][tm << 2];
          double w0 = (double)wv.x, w1 = (double)wv.y;
          double w2 = (double)wv.z, w3 = (double)wv.w;
#pragma unroll
          for (int pi = 0; pi < 4; ++pi) {
            double xc = xd[pi + kx];
            acc[pi][0] = fma(xc, w0, acc[pi][0]);
            acc[pi][1] = fma(xc, w1, acc[pi][1]);
            acc[pi][2] = fma(xc, w2, acc[pi][2]);
            acc[pi][3] = fma(xc, w3, acc[pi][3]);
          }
        }
      }
    }
    __syncthreads();
  }

  // per-op fp32 chain: cast conv result, then +bias, relu, *mask
  float4 bv = *(const float4*)&bias[m0 + (tm << 2)];
  float hv[4][4];
#pragma unroll
  for (int pi = 0; pi < 4; ++pi) {
    int col = xb + (tp << 2) + pi;
    float mv = (float)mask[y * WW + col];
    hv[pi][0] = __fmul_rn(fmaxf(__fadd_rn((float)acc[pi][0], bv.x), 0.f), mv);
    hv[pi][1] = __fmul_rn(fmaxf(__fadd_rn((float)acc[pi][1], bv.y), 0.f), mv);
    hv[pi][2] = __fmul_rn(fmaxf(__fadd_rn((float)acc[pi][2], bv.z), 0.f), mv);
    hv[pi][3] = __fmul_rn(fmaxf(__fadd_rn((float)acc[pi][3], bv.w), 0.f), mv);
  }

  // 12 head partial dots over this block's 64 m-channels (fp64-exact over fp32 h)
  int pixbase = y * WW + xb + (tp << 2);
#pragma unroll
  for (int r = 0; r < 12; ++r) {
    const float* wr = &w12[r][tm << 2];
    double w0 = (double)wr[0], w1 = (double)wr[1];
    double w2 = (double)wr[2], w3 = (double)wr[3];
#pragma unroll
    for (int pi = 0; pi < 4; ++pi) {
      double t = (double)hv[pi][0] * w0 + (double)hv[pi][1] * w1 +
                 (double)hv[pi][2] * w2 + (double)hv[pi][3] * w3;
#pragma unroll
      for (int off = 8; off; off >>= 1) t += __shfl_down(t, off, 16);
      if (tm == 0) atomicAdd(&logits[(size_t)(pixbase + pi) * 12 + r], t);
    }
  }
}

// ------- finalize per pixel: FULL f64 softmax/argmax/sigmoid, cast to f32 -----
__global__ __launch_bounds__(256) void finalize_kernel(
    const double* __restrict__ logits, const float* __restrict__ loc_b,
    const float* __restrict__ cls_b, const float* __restrict__ cos_b,
    float* __restrict__ out, float* __restrict__ fg32,
    float* __restrict__ ascale, int* __restrict__ assign) {
  int p = blockIdx.x * 256 + threadIdx.x;
  const double* lg = &logits[(size_t)p * 12];
#pragma unroll
  for (int o = 0; o < 4; ++o)
    out[O_LOCS + p * 4 + o] = (float)(lg[o] + (double)loc_b[o]);
  double cl[7];
#pragma unroll
  for (int i = 0; i < 7; ++i) {
    cl[i] = lg[4 + i] + (double)cls_b[i];
    out[O_CLS + p * 7 + i] = (float)cl[i];
  }
  double z = lg[11] + (double)cos_b[0];
  double sig = 1.0 / (1.0 + exp(-z));
  out[O_COS + p] = (float)sig;
  // exact argmax on f64 logits (== argmax of softmax p), ties -> first index
  double pm = cl[0];
  int ai = 0;
#pragma unroll
  for (int i = 1; i < 7; ++i)
    if (cl[i] > pm) { pm = cl[i]; ai = i; }
  // f64 softmax for fg, single cast to f32
  double mx = cl[0];
#pragma unroll
  for (int i = 1; i < 7; ++i) mx = fmax(mx, cl[i]);
  double S = 0.0;
#pragma unroll
  for (int i = 0; i < 7; ++i) S += exp(cl[i] - mx);
  double p0 = exp(cl[0] - mx) / S;
  fg32[p] = (float)(1.0 - p0);
  assign[p] = ai;
  const float BS[7] = {16.f, 9.f, 14.f, 21.f, 33.f, 54.f, 93.f};
  ascale[p] = BS[ai];
}

// -------- anchors, loc2bbox, clip, validity, scores — fp32 op-for-op ----------
__global__ __launch_bounds__(256) void roi_kernel(
    float* __restrict__ out, const float* __restrict__ fg32,
    const float* __restrict__ ascale, const int* __restrict__ assign,
    const int* __restrict__ img_h, const int* __restrict__ img_w,
    float* __restrict__ roi, float* __restrict__ scores32) {
  int p = blockIdx.x * 256 + threadIdx.x;
  float a0 = out[O_COS + 0];
  if (a0 == 0.0f) a0 = __fadd_rn(a0, 1e-5f);
  float t1 = __fmul_rn(a0, a0);
  float t2 = __fdiv_rn(1.0f, t1);
  float t3 = __fsub_rn(t2, 1.0f);
  float anchor_h = __fmul_rn(ascale[0], sqrt32(t3));
  float anchor_w = ascale[p];
  float ay = __fadd_rn((float)(p >> 7) * 8.0f, 4.0f);
  float ax = __fadd_rn((float)(p & 127) * 8.0f, 4.0f);
  float A0 = __fsub_rn(ay, __fmul_rn(0.5f, anchor_h));
  float A1 = __fsub_rn(ax, __fmul_rn(0.5f, anchor_w));
  float A2 = __fadd_rn(ay, __fmul_rn(0.5f, anchor_h));
  float A3 = __fadd_rn(ax, __fmul_rn(0.5f, anchor_w));
  *(float4*)&out[O_ANCHOR + p * 4] = make_float4(A0, A1, A2, A3);
  float hA = __fsub_rn(A2, A0), wA = __fsub_rn(A3, A1);
  float cy = __fadd_rn(A0, __fmul_rn(0.5f, hA));
  float cx = __fadd_rn(A1, __fmul_rn(0.5f, wA));
  float l0 = out[O_LOCS + p * 4 + 0], l1 = out[O_LOCS + p * 4 + 1];
  float l2 = out[O_LOCS + p * 4 + 2], l3 = out[O_LOCS + p * 4 + 3];
  float ncy = __fadd_rn(__fmul_rn(l0, hA), cy);
  float ncx = __fadd_rn(__fmul_rn(l1, wA), cx);
  float nh = __fmul_rn(exp32(l2), hA);
  float nw = __fmul_rn(exp32(l3), wA);
  float b0 = __fsub_rn(ncy, __fmul_rn(0.5f, nh));
  float b1 = __fsub_rn(ncx, __fmul_rn(0.5f, nw));
  float b2 = __fadd_rn(ncy, __fmul_rn(0.5f, nh));
  float b3 = __fadd_rn(ncx, __fmul_rn(0.5f, nw));
  float IH = (float)img_h[0], IW = (float)img_w[0];
  b0 = fminf(fmaxf(b0, 0.f), IH);
  b1 = fminf(fmaxf(b1, 0.f), IW);
  b2 = fminf(fmaxf(b2, 0.f), IH);
  b3 = fminf(fmaxf(b3, 0.f), IW);
  *(float4*)&roi[p * 4] = make_float4(b0, b1, b2, b3);
  float hs = __fsub_rn(b2, b0), wd = __fsub_rn(b3, b1);
  bool valid = (assign[p] > 0) && (hs >= 16.f) && (wd >= 16.f);
  scores32[p] = valid ? fg32[p] : -INFINITY;
}

// ----- stable descending sort (bitonic) on fp32 score bits + index asc -------
__global__ __launch_bounds__(1024) void sort_kernel(
    const float* __restrict__ scores32, const float* __restrict__ roi,
    float* __restrict__ out, float* __restrict__ cand, float* __restrict__ tops) {
  __shared__ unsigned long long keys[16384];
  int tid = threadIdx.x;
  for (int i = tid; i < 16384; i += 1024) {
    unsigned u = __float_as_uint(scores32[i]);
    u = (u & 0x80000000u) ? ~u : (u | 0x80000000u);
    keys[i] = ((unsigned long long)(~u) << 32) | (unsigned)i;
  }
  __syncthreads();
  for (int k = 2; k <= 16384; k <<= 1) {
    for (int j = k >> 1; j > 0; j >>= 1) {
      for (int i = tid; i < 16384; i += 1024) {
        int l = i ^ j;
        if (l > i) {
          unsigned long long a = keys[i], b = keys[l];
          bool up = ((i & k) == 0);
          if ((a > b) == up) { keys[i] = b; keys[l] = a; }
        }
      }
      __syncthreads();
    }
  }
  for (int t = tid; t < NPRE; t += 1024) {
    int idx = (int)(keys[t] & 0x3FFFull);
    float s = scores32[idx];
    float4 b = make_float4(0.f, 0.f, 0.f, 0.f);
    if (isfinite(s)) b = *(const float4*)&roi[idx * 4];
    ((float4*)(out + O_OLD))[t] = b;
    ((float4*)cand)[t] = b;
    tops[t] = s;
  }
}

// ---------------- sequential NMS, pure fp32 op-for-op -------------------------
__global__ __launch_bounds__(1024) void nms_kernel(const float* __restrict__ cand,
                                                   const float* __restrict__ tops,
                                                   float* __restrict__ out) {
  __shared__ float sy0[NPRE], sx0[NPRE], sy1[NPRE], sx1[NPRE], sar[NPRE], cur[NPRE];
  __shared__ unsigned long long red[16];
  __shared__ unsigned long long bestk;
  int tid = threadIdx.x;
  for (int i = tid; i < NPRE; i += 1024) {
    float4 b = ((const float4*)cand)[i];
    sy0[i] = b.x; sx0[i] = b.y; sy1[i] = b.z; sx1[i] = b.w;
    sar[i] = __fmul_rn(__fsub_rn(b.z, b.x), __fsub_rn(b.w, b.y));
    cur[i] = tops[i];
  }
  __syncthreads();
  int lane = tid & 63, wid = tid >> 6;
  for (int k = 0; k < NPOST; ++k) {
    unsigned long long best = 0;
    for (int i = tid; i < NPRE; i += 1024) {
      unsigned u = __float_as_uint(cur[i]);
      u = (u & 0x80000000u) ? ~u : (u | 0x80000000u);
      unsigned long long key =
          ((unsigned long long)u << 32) | (unsigned)(NPRE - i);  // tie -> lowest idx
      if (key > best) best = key;
    }
#pragma unroll
    for (int off = 32; off; off >>= 1) {
      unsigned long long o = __shfl_xor(best, off, 64);
      if (o > best) best = o;
    }
    if (lane == 0) red[wid] = best;
    __syncthreads();
    if (tid == 0) {
      unsigned long long b = red[0];
      for (int w2 = 1; w2 < 16; ++w2)
        if (red[w2] > b) b = red[w2];
      bestk = b;
    }
    __syncthreads();
    unsigned long long b = bestk;
    int i = NPRE - (int)(b & 0xFFFFFFFFull);
    bool valid = (unsigned)(b >> 32) > 0x007FFFFFu;  // score > -inf
    float by0 = sy0[i], bx0 = sx0[i], by1 = sy1[i], bx1 = sx1[i], bar = sar[i];
    for (int j = tid; j < NPRE; j += 1024) {
      float yy0 = fmaxf(sy0[j], by0), xx0 = fmaxf(sx0[j], bx0);
      float yy1 = fminf(sy1[j], by1), xx1 = fminf(sx1[j], bx1);
      float inter = __fmul_rn(fmaxf(__fsub_rn(yy1, yy0), 0.f),
                              fmaxf(__fsub_rn(xx1, xx0), 0.f));
      float den = __fadd_rn(__fsub_rn(__fadd_rn(sar[j], bar), inter), 1e-9f);
      float iou = __fdiv_rn(inter, den);
      if (iou > 0.7f) cur[j] = -INFINITY;
    }
    if (tid == 0) {
      if (valid) {
        out[O_ROIS + k * 4 + 0] = by0;
        out[O_ROIS + k * 4 + 1] = bx0;
        out[O_ROIS + k * 4 + 2] = by1;
        out[O_ROIS + k * 4 + 3] = bx1;
        out[O_RSC + k] = tops[i];
      } else {
        out[O_ROIS + k * 4 + 0] = 0.f;
        out[O_ROIS + k * 4 + 1] = 0.f;
        out[O_ROIS + k * 4 + 2] = 0.f;
        out[O_ROIS + k * 4 + 3] = 0.f;
        out[O_RSC + k] = 0.f;
      }
    }
    __syncthreads();
  }
  for (int t = tid; t < NPOST; t += 1024) out[O_RIDX + t] = 0.f;
}

extern "C" void kernel_launch(void* const* d_in, const int* in_sizes, int n_in,
                              void* d_out, int out_size, void* d_ws, size_t ws_size,
                              hipStream_t stream) {
  (void)in_sizes; (void)n_in; (void)out_size; (void)ws_size;
  const float* x      = (const float*)d_in[0];
  const int*   skel   = (const int*)d_in[1];
  const float* conv_w = (const float*)d_in[2];
  const float* conv_b = (const float*)d_in[3];
  const float* loc_w  = (const float*)d_in[4];
  const float* loc_b  = (const float*)d_in[5];
  const float* cls_w  = (const float*)d_in[6];
  const float* cls_b  = (const float*)d_in[7];
  const float* cos_w  = (const float*)d_in[8];
  const float* cos_b  = (const float*)d_in[9];
  const int*   img_h  = (const int*)d_in[10];
  const int*   img_w  = (const int*)d_in[11];
  float* out = (float*)d_out;
  float* ws  = (float*)d_ws;

  float*  wt       = ws + WS_WT;
  double* logits   = (double*)(ws + WS_LOG);
  float*  fg32     = ws + WS_FG32;
  float*  ascale   = ws + WS_ASCALE;
  int*    assign   = (int*)(ws + WS_ASSIGN);
  float*  roi      = ws + WS_ROI;
  float*  scores32 = ws + WS_SC32;
  float*  cand     = ws + WS_CAND;
  float*  tops     = ws + WS_TOPS;

  hipLaunchKernelGGL(zero_kernel, dim3(192), dim3(1024), 0, stream, logits, NPIX * 12);
  hipLaunchKernelGGL(wt_kernel, dim3(72, 8), dim3(256), 0, stream, conv_w, wt);
  hipLaunchKernelGGL(conv_heads_kernel, dim3(256, 8), dim3(256), 0, stream, x, wt,
                     conv_b, skel, loc_w, cls_w, cos_w, logits);
  hipLaunchKernelGGL(finalize_kernel, dim3(64), dim3(256), 0, stream, logits, loc_b,
                     cls_b, cos_b, out, fg32, ascale, assign);
  hipLaunchKernelGGL(roi_kernel, dim3(64), dim3(256), 0, stream, out, fg32, ascale,
                     assign, img_h, img_w, roi, scores32);
  hipLaunchKernelGGL(sort_kernel, dim3(1), dim3(1024), 0, stream, scores32, roi, out,
                     cand, tops);
  hipLaunchKernelGGL(nms_kernel, dim3(1), dim3(1024), 0, stream, cand, tops, out);
}